// Round 2
// baseline (57.883 us; speedup 1.0000x reference)
//
#include <hip/hip_runtime.h>

#define HW    262144          // 512*512
#define CHW   786432          // 3*HW
#define NBINS 256
#define PBB   32              // partial-hist blocks per batch
#define CHUNK (HW / PBB)      // 8192 elements per block

// ---------------- Kernel 1: per-batch partial histograms ----------------
// Bank-exclusive layout: lh[bin*32 + col], col = lane&31 -> bank == lane%32,
// zero LDS bank conflicts on the atomic path by construction.
__global__ __launch_bounds__(256) void hist_part_kernel(const float* __restrict__ x,
                                                        unsigned int* __restrict__ part) {
    __shared__ unsigned int lh[NBINS * 32];   // 32 KB
    const int tid = threadIdx.x;
    const int col = tid & 31;
    for (int i = tid; i < NBINS * 32; i += 256) lh[i] = 0u;
    __syncthreads();

    const int b = blockIdx.x >> 5;            // / PBB
    const int p = blockIdx.x & (PBB - 1);
    // channel 0 of batch b is the first HW floats of its CHW stride
    const float4* src = (const float4*)(x + (size_t)b * CHW + (size_t)p * CHUNK);

    for (int i = tid; i < CHUNK / 4; i += 256) {
        float4 v = src[i];
        float vv[4] = {v.x, v.y, v.z, v.w};
#pragma unroll
        for (int j = 0; j < 4; ++j) {
            float f  = vv[j];
            int idx  = (int)floorf(f * 256.0f);          // matches jnp.floor(flat*256)
            idx = idx < 0 ? 0 : (idx > 255 ? 255 : idx); // clip to [0,255]
            if (f >= 0.0f && f <= 1.0f) atomicAdd(&lh[idx * 32 + col], 1u);
        }
    }
    __syncthreads();

    // Reduce 32 columns per bin; rotate start col per row so lane t reads
    // bank (t+i)&31 -> 2 lanes/bank (free), no 64-way conflict.
    unsigned int* out = part + (size_t)blockIdx.x * NBINS;
    {
        const int t = tid;                    // 256 threads == 256 bins
        unsigned int s = 0;
#pragma unroll
        for (int i = 0; i < 32; ++i) s += lh[t * 32 + ((t + i) & 31)];
        out[t] = s;
    }
}

// ---------------- Kernel 2: reduce partials + layer 1 (pre-BN) ----------------
__global__ __launch_bounds__(128) void l1_kernel(const unsigned int* __restrict__ part,
                                                 const float* __restrict__ W1,
                                                 const float* __restrict__ b1,
                                                 float* __restrict__ h1pre) {
    __shared__ float row[NBINS];
    const int tid = threadIdx.x;   // 128 = output features of layer 1
    const int b   = blockIdx.x;    // 64 batches

    for (int k = tid; k < NBINS; k += 128) {
        unsigned int s = 0;
        const unsigned int* pp = part + ((size_t)b * PBB) * NBINS + k;
#pragma unroll
        for (int p = 0; p < PBB; ++p) s += pp[(size_t)p * NBINS];
        row[k] = (float)s;
    }
    __syncthreads();

    // total count (hist.sum(axis=1)) — all threads compute the same value
    float S = 0.0f;
    for (int k = 0; k < NBINS; ++k) S += row[k];
    const float inv = 1.0f / (S + 1e-6f);

    const float* w = W1 + (size_t)tid * NBINS;
    float a0 = 0.f, a1 = 0.f, a2 = 0.f, a3 = 0.f;
    for (int k = 0; k < NBINS; k += 4) {
        a0 += row[k + 0] * w[k + 0];
        a1 += row[k + 1] * w[k + 1];
        a2 += row[k + 2] * w[k + 2];
        a3 += row[k + 3] * w[k + 3];
    }
    h1pre[b * 128 + tid] = (a0 + a1 + a2 + a3) * inv + b1[tid];
}

// ---------------- Kernel 3: BN1+ReLU -> L2 -> BN2+ReLU -> L3 ----------------
__global__ __launch_bounds__(1024) void mlp_kernel(const float* __restrict__ h1pre,
                                                   const float* __restrict__ g1,
                                                   const float* __restrict__ be1,
                                                   const float* __restrict__ W2,
                                                   const float* __restrict__ b2,
                                                   const float* __restrict__ g2,
                                                   const float* __restrict__ be2,
                                                   const float* __restrict__ W3,
                                                   const float* __restrict__ b3,
                                                   float* __restrict__ out) {
    __shared__ float h1[64 * 128];
    __shared__ float h2[64 * 64];
    __shared__ float sc1[128], sh1[128];
    __shared__ float sc2[64],  sh2[64];
    const int tid = threadIdx.x;

    for (int i = tid; i < 8192; i += 1024) h1[i] = h1pre[i];
    __syncthreads();

    // BN1 stats (biased var, training mode)
    if (tid < 128) {
        float s = 0.f, sq = 0.f;
        for (int b = 0; b < 64; ++b) { float v = h1[b * 128 + tid]; s += v; sq += v * v; }
        float mu  = s * (1.0f / 64.0f);
        float var = sq * (1.0f / 64.0f) - mu * mu;
        float sc  = g1[tid] * rsqrtf(var + 1e-5f);
        sc1[tid] = sc;
        sh1[tid] = be1[tid] - mu * sc;
    }
    __syncthreads();

    for (int i = tid; i < 8192; i += 1024) {
        int j = i & 127;
        h1[i] = fmaxf(h1[i] * sc1[j] + sh1[j], 0.0f);
    }
    __syncthreads();

    // Layer 2: (64,128) @ (64,128)^T -> (64,64)
    for (int i = tid; i < 4096; i += 1024) {
        int b = i >> 6, j = i & 63;
        const float* w  = W2 + (size_t)j * 128;
        const float* hr = h1 + b * 128;
        float a0 = 0.f, a1 = 0.f, a2 = 0.f, a3 = 0.f;
        for (int k = 0; k < 128; k += 4) {
            a0 += hr[k + 0] * w[k + 0];
            a1 += hr[k + 1] * w[k + 1];
            a2 += hr[k + 2] * w[k + 2];
            a3 += hr[k + 3] * w[k + 3];
        }
        h2[i] = (a0 + a1 + a2 + a3) + b2[j];
    }
    __syncthreads();

    // BN2 stats
    if (tid < 64) {
        float s = 0.f, sq = 0.f;
        for (int b = 0; b < 64; ++b) { float v = h2[b * 64 + tid]; s += v; sq += v * v; }
        float mu  = s * (1.0f / 64.0f);
        float var = sq * (1.0f / 64.0f) - mu * mu;
        float sc  = g2[tid] * rsqrtf(var + 1e-5f);
        sc2[tid] = sc;
        sh2[tid] = be2[tid] - mu * sc;
    }
    __syncthreads();

    for (int i = tid; i < 4096; i += 1024) {
        int j = i & 63;
        h2[i] = fmaxf(h2[i] * sc2[j] + sh2[j], 0.0f);
    }
    __syncthreads();

    // Layer 3: (64,64) @ (1,64)^T + b3 -> (64,1)
    if (tid < 64) {
        const float* hr = h2 + tid * 64;
        float acc = b3[0];
        for (int k = 0; k < 64; ++k) acc += hr[k] * W3[k];
        out[tid] = acc;
    }
}

extern "C" void kernel_launch(void* const* d_in, const int* in_sizes, int n_in,
                              void* d_out, int out_size, void* d_ws, size_t ws_size,
                              hipStream_t stream) {
    const float* x   = (const float*)d_in[0];
    const float* W1  = (const float*)d_in[1];
    const float* b1  = (const float*)d_in[2];
    const float* g1  = (const float*)d_in[3];
    const float* be1 = (const float*)d_in[4];
    const float* W2  = (const float*)d_in[5];
    const float* b2  = (const float*)d_in[6];
    const float* g2  = (const float*)d_in[7];
    const float* be2 = (const float*)d_in[8];
    const float* W3  = (const float*)d_in[9];
    const float* b3  = (const float*)d_in[10];
    float* out = (float*)d_out;

    unsigned int* part = (unsigned int*)d_ws;                       // 2048*256*4 = 2 MB
    float* h1pre       = (float*)((char*)d_ws + (2u << 20));        // 8192 floats

    hipLaunchKernelGGL(hist_part_kernel, dim3(64 * PBB), dim3(256), 0, stream, x, part);
    hipLaunchKernelGGL(l1_kernel,        dim3(64),       dim3(128), 0, stream, part, W1, b1, h1pre);
    hipLaunchKernelGGL(mlp_kernel,       dim3(1),        dim3(1024), 0, stream,
                       h1pre, g1, be1, W2, b2, g2, be2, W3, b3, out);
}

// Round 3
// 48.468 us; speedup vs baseline: 1.1942x; 1.1942x over previous
//
#include <hip/hip_runtime.h>

#define HW    262144          // 512*512
#define CHW   786432          // 3*HW
#define NBINS 256
#define PBB   16              // partial-hist blocks per batch
#define CHUNK (HW / PBB)      // 16384 elements per block

// ---------------- Kernel 1: per-batch partial histograms ----------------
// Bank-exclusive layout: lh[bin*32 + col], col = lane&31 -> bank == lane%32.
__global__ __launch_bounds__(256) void hist_part_kernel(const float* __restrict__ x,
                                                        unsigned int* __restrict__ part) {
    __shared__ unsigned int lh[NBINS * 32];   // 32 KB
    const int tid = threadIdx.x;
    const int col = tid & 31;
    for (int i = tid; i < NBINS * 32; i += 256) lh[i] = 0u;
    __syncthreads();

    const int b = blockIdx.x >> 4;            // / PBB
    const int p = blockIdx.x & (PBB - 1);
    const float4* src = (const float4*)(x + (size_t)b * CHW + (size_t)p * CHUNK);

    for (int i = tid; i < CHUNK / 4; i += 256) {
        float4 v = src[i];
        float vv[4] = {v.x, v.y, v.z, v.w};
#pragma unroll
        for (int j = 0; j < 4; ++j) {
            float f  = vv[j];
            int idx  = (int)floorf(f * 256.0f);
            idx = idx < 0 ? 0 : (idx > 255 ? 255 : idx);
            if (f >= 0.0f && f <= 1.0f) atomicAdd(&lh[idx * 32 + col], 1u);
        }
    }
    __syncthreads();

    unsigned int* out = part + (size_t)blockIdx.x * NBINS;
    {
        const int t = tid;
        unsigned int s = 0;
#pragma unroll
        for (int i = 0; i < 32; ++i) s += lh[t * 32 + ((t + i) & 31)];
        out[t] = s;
    }
}

// ---------------- Kernel 2: reduce partials + layer 1 (pre-BN) ----------------
// W1 staged in LDS (pad-260 stride, bank-even b128 reads). One block per batch.
#define W1P 260
__global__ __launch_bounds__(256) void l1_kernel(const unsigned int* __restrict__ part,
                                                 const float* __restrict__ W1,
                                                 const float* __restrict__ b1,
                                                 float* __restrict__ h1pre) {
    __shared__ float wl[128 * W1P];           // 130 KB
    __shared__ float row[NBINS];
    __shared__ float pd[256];
    __shared__ float sred[4];
    const int tid = threadIdx.x;
    const int b   = blockIdx.x;

    // stage W1 (128x256) -> wl padded, coalesced float4
    {
        const float4* w4 = (const float4*)W1;
        for (int idx4 = tid; idx4 < 128 * 64; idx4 += 256) {
            int r = idx4 >> 6, c4 = (idx4 & 63) << 2;
            *(float4*)&wl[r * W1P + c4] = w4[idx4];
        }
    }

    // reduce PBB partials -> row (coalesced across threads)
    {
        const int k = tid;                    // 256 threads == 256 bins
        unsigned int s = 0;
        const unsigned int* pp = part + ((size_t)b * PBB) * NBINS + k;
#pragma unroll
        for (int p = 0; p < PBB; ++p) s += pp[(size_t)p * NBINS];
        row[k] = (float)s;
    }
    __syncthreads();

    // total count S via wave butterfly + LDS combine
    {
        float s = row[tid];
        for (int off = 32; off > 0; off >>= 1) s += __shfl_down(s, off);
        if ((tid & 63) == 0) sred[tid >> 6] = s;
    }
    __syncthreads();
    const float S   = sred[0] + sred[1] + sred[2] + sred[3];
    const float inv = 1.0f / (S + 1e-6f);

    // dot: thread = (feature j, half h); wl reads bank-even, row reads uniform
    {
        const int j = tid & 127;
        const int h = tid >> 7;
        const float* w = &wl[j * W1P + h * 128];
        const float* r = &row[h * 128];
        float a0 = 0.f, a1 = 0.f, a2 = 0.f, a3 = 0.f;
#pragma unroll
        for (int k = 0; k < 128; k += 4) {
            float4 wv = *(const float4*)&w[k];
            float4 rv = *(const float4*)&r[k];
            a0 += wv.x * rv.x; a1 += wv.y * rv.y;
            a2 += wv.z * rv.z; a3 += wv.w * rv.w;
        }
        pd[tid] = (a0 + a1) + (a2 + a3);
    }
    __syncthreads();

    if (tid < 128)
        h1pre[b * 128 + tid] = (pd[tid] + pd[tid + 128]) * inv + b1[tid];
}

// ---------------- Kernel 3: BN1+ReLU -> L2 -> BN2+ReLU -> L3 ----------------
// h1 stride 132, h2 stride 68 (banks 4b+k: even spread, 16B aligned).
// Weight rows are wave-uniform (j from wave id); batch is the lane index.
#define H1P 132
#define H2P 68
__global__ __launch_bounds__(1024) void mlp_kernel(const float* __restrict__ h1pre,
                                                   const float* __restrict__ g1,
                                                   const float* __restrict__ be1,
                                                   const float* __restrict__ W2,
                                                   const float* __restrict__ b2,
                                                   const float* __restrict__ g2,
                                                   const float* __restrict__ be2,
                                                   const float* __restrict__ W3,
                                                   const float* __restrict__ b3,
                                                   float* __restrict__ out) {
    __shared__ float h1[64 * H1P];
    __shared__ float h2[64 * H2P];
    __shared__ float sc1[128], sh1[128];
    __shared__ float sc2[64],  sh2[64];
    const int tid = threadIdx.x;

    // A: load h1pre (64x128) -> padded LDS, float4
    {
        const float4* src = (const float4*)h1pre;
        for (int idx4 = tid; idx4 < 2048; idx4 += 1024) {
            int r = idx4 >> 5, c4 = (idx4 & 31) << 2;
            *(float4*)&h1[r * H1P + c4] = src[idx4];
        }
    }
    __syncthreads();

    // B: BN1 stats (feature = lane, conflict-free column reads)
    if (tid < 128) {
        float s = 0.f, sq = 0.f;
        for (int b = 0; b < 64; ++b) { float v = h1[b * H1P + tid]; s += v; sq += v * v; }
        float mu  = s * (1.0f / 64.0f);
        float var = sq * (1.0f / 64.0f) - mu * mu;
        float sc  = g1[tid] * rsqrtf(var + 1e-5f);
        sc1[tid] = sc;
        sh1[tid] = be1[tid] - mu * sc;
    }
    __syncthreads();

    // B2: normalize + ReLU in place
    for (int idx4 = tid; idx4 < 2048; idx4 += 1024) {
        int r = idx4 >> 5, c4 = (idx4 & 31) << 2;
        float4 v = *(const float4*)&h1[r * H1P + c4];
        v.x = fmaxf(v.x * sc1[c4 + 0] + sh1[c4 + 0], 0.f);
        v.y = fmaxf(v.y * sc1[c4 + 1] + sh1[c4 + 1], 0.f);
        v.z = fmaxf(v.z * sc1[c4 + 2] + sh1[c4 + 2], 0.f);
        v.w = fmaxf(v.w * sc1[c4 + 3] + sh1[c4 + 3], 0.f);
        *(float4*)&h1[r * H1P + c4] = v;
    }
    __syncthreads();

    // C: layer 2. b = lane (t&63), wave w = t>>6 owns features j0..j0+3 (wave-uniform)
    {
        const int b  = tid & 63;
        const int w  = tid >> 6;
        const int j0 = w << 2;
        float acc0 = b2[j0 + 0], acc1 = b2[j0 + 1], acc2 = b2[j0 + 2], acc3 = b2[j0 + 3];
#pragma unroll
        for (int c = 0; c < 4; ++c) {
            const int k0 = c * 32;
            float4 xv[8];
#pragma unroll
            for (int i = 0; i < 8; ++i) xv[i] = *(const float4*)&h1[b * H1P + k0 + 4 * i];
#pragma unroll
            for (int p = 0; p < 4; ++p) {
                const float4* wr = (const float4*)(W2 + (size_t)(j0 + p) * 128 + k0);
                float a = 0.f;
#pragma unroll
                for (int i = 0; i < 8; ++i) {
                    float4 wv = wr[i];
                    a += xv[i].x * wv.x + xv[i].y * wv.y + xv[i].z * wv.z + xv[i].w * wv.w;
                }
                if (p == 0) acc0 += a; else if (p == 1) acc1 += a;
                else if (p == 2) acc2 += a; else acc3 += a;
            }
        }
        h2[b * H2P + j0 + 0] = acc0;
        h2[b * H2P + j0 + 1] = acc1;
        h2[b * H2P + j0 + 2] = acc2;
        h2[b * H2P + j0 + 3] = acc3;
    }
    __syncthreads();

    // E: BN2 stats
    if (tid < 64) {
        float s = 0.f, sq = 0.f;
        for (int b = 0; b < 64; ++b) { float v = h2[b * H2P + tid]; s += v; sq += v * v; }
        float mu  = s * (1.0f / 64.0f);
        float var = sq * (1.0f / 64.0f) - mu * mu;
        float sc  = g2[tid] * rsqrtf(var + 1e-5f);
        sc2[tid] = sc;
        sh2[tid] = be2[tid] - mu * sc;
    }
    __syncthreads();

    // F: normalize + ReLU + layer 3 (one lane per batch)
    if (tid < 64) {
        const int b = tid;
        float acc = b3[0];
#pragma unroll
        for (int k0 = 0; k0 < 64; k0 += 4) {
            float4 v = *(const float4*)&h2[b * H2P + k0];
            float4 wv = *(const float4*)&W3[k0];
            acc += fmaxf(v.x * sc2[k0 + 0] + sh2[k0 + 0], 0.f) * wv.x;
            acc += fmaxf(v.y * sc2[k0 + 1] + sh2[k0 + 1], 0.f) * wv.y;
            acc += fmaxf(v.z * sc2[k0 + 2] + sh2[k0 + 2], 0.f) * wv.z;
            acc += fmaxf(v.w * sc2[k0 + 3] + sh2[k0 + 3], 0.f) * wv.w;
        }
        out[b] = acc;
    }
}

extern "C" void kernel_launch(void* const* d_in, const int* in_sizes, int n_in,
                              void* d_out, int out_size, void* d_ws, size_t ws_size,
                              hipStream_t stream) {
    const float* x   = (const float*)d_in[0];
    const float* W1  = (const float*)d_in[1];
    const float* b1  = (const float*)d_in[2];
    const float* g1  = (const float*)d_in[3];
    const float* be1 = (const float*)d_in[4];
    const float* W2  = (const float*)d_in[5];
    const float* b2  = (const float*)d_in[6];
    const float* g2  = (const float*)d_in[7];
    const float* be2 = (const float*)d_in[8];
    const float* W3  = (const float*)d_in[9];
    const float* b3  = (const float*)d_in[10];
    float* out = (float*)d_out;

    unsigned int* part = (unsigned int*)d_ws;                       // 1024*256*4 = 1 MB
    float* h1pre       = (float*)((char*)d_ws + (1u << 20));        // 8192 floats

    hipLaunchKernelGGL(hist_part_kernel, dim3(64 * PBB), dim3(256), 0, stream, x, part);
    hipLaunchKernelGGL(l1_kernel,        dim3(64),       dim3(256), 0, stream, part, W1, b1, h1pre);
    hipLaunchKernelGGL(mlp_kernel,       dim3(1),        dim3(1024), 0, stream,
                       h1pre, g1, be1, W2, b2, g2, be2, W3, b3, out);
}